// Round 3
// baseline (443.372 us; speedup 1.0000x reference)
//
#include <hip/hip_runtime.h>

constexpr int   T   = 4096;
constexpr float VTH = 1.27f;
constexpr int   K   = 16;        // time chunks per row
constexpr int   L   = T / K;     // 256 steps per chunk
constexpr int   W   = 192;       // speculative warm-up steps (lock window)
constexpr int   LG  = L / 4;     // 64 float4 groups per chunk
constexpr int   WG  = W / 4;     // 48 warm-up groups

// One LIF step (validated bit-exact in R2, absmax 0.0).
// v: membrane (0 carried out of a spike step); u: countdown (7 after spike at t>=1).
//   x zeroed this step iff u_entry >= 3 ; dv[t-1] zeroed iff u_exit > 0
__device__ __forceinline__ bool lif_step(float x, float decay, float& v, float& u,
                                         float& vo, float& so, float& dvo, float xprev,
                                         bool setu) {
    float t1 = __fmul_rn(decay, v);
    float vd = __fsub_rn(v, t1);           // unfused — matches reference rounding
    float xe = (u >= 3.0f) ? 0.0f : x;
    float vn = __fadd_rn(vd, xe);
    bool  s  = vn > VTH;
    vo = s ? VTH  : vn;
    so = s ? 1.0f : 0.0f;
    v  = s ? 0.0f : vn;
    float us = (setu && s) ? 8.0f : u;
    u = fmaxf(us - 1.0f, 0.0f);
    dvo = (u > 0.0f) ? 0.0f : xprev;
    return s;
}

// 4 steps. close = dv[t-1] (finalizes previous group); px,py,pz = dv[t..t+2].
__device__ __forceinline__ void group4(float4 X, float decay, float& v, float& u,
                                       float& xprev, float4& vo, float4& so,
                                       float& close, float& px, float& py, float& pz) {
    lif_step(X.x, decay, v, u, vo.x, so.x, close, xprev, true); xprev = X.x;
    lif_step(X.y, decay, v, u, vo.y, so.y, px,    xprev, true); xprev = X.y;
    lif_step(X.z, decay, v, u, vo.z, so.z, py,    xprev, true); xprev = X.z;
    lif_step(X.w, decay, v, u, vo.w, so.w, pz,    xprev, true); xprev = X.w;
}

// ---------------- speculative chunk kernel ----------------
__global__ __launch_bounds__(64, 1)
void lif_spec(const float* __restrict__ ode, const float* __restrict__ decay_p,
              float* __restrict__ vout, float* __restrict__ sout,
              float* __restrict__ dvout,
              float2* __restrict__ Sst, float2* __restrict__ Est, int B) {
    const int g = blockIdx.x * 64 + threadIdx.x;
    const int b = g % B;            // lanes = consecutive rows (coalesced S/E writes)
    const int k = g / B;
    const float decay = decay_p[0];

    const size_t bt = (size_t)b * T;
    const float4* __restrict__ x4 = (const float4*)(ode + bt);
    float4* __restrict__ v4 = (float4*)(vout + bt);
    float4* __restrict__ s4 = (float4*)(sout + bt);
    float4* __restrict__ d4 = (float4*)(dvout + bt);

    const int wg = (k == 0) ? 0 : WG;      // warm-up groups for this chunk
    const int ng = wg + LG;                // total groups (64 or 112, both %8==0)
    const int m0 = k * LG - wg;            // first float4 index

    float v = 0.0f, u = 0.0f, xprev = 0.0f;
    float4 pend;

    // explicit 8-deep prefetch ring (NO arrays — avoid scratch demotion)
    float4 X0 = x4[m0 + 0], X1 = x4[m0 + 1], X2 = x4[m0 + 2], X3 = x4[m0 + 3];
    float4 X4v = x4[m0 + 4], X5 = x4[m0 + 5], X6 = x4[m0 + 6], X7 = x4[m0 + 7];

#define STAGE(i, Xi)                                                           \
    {                                                                          \
        const int gi = gg + (i);                                               \
        const int m  = m0 + gi;                                                \
        float4 vo, so; float close, px, py, pz;                                \
        if (k == 0 && gi == 0) {                                               \
            float dvd;                                                         \
            bool s0 = lif_step(Xi.x, decay, v, u, vo.x, so.x, dvd, xprev, false); xprev = Xi.x; \
            bool s1 = lif_step(Xi.y, decay, v, u, vo.y, so.y, px,  xprev, true ); xprev = Xi.y; \
            lif_step(Xi.z, decay, v, u, vo.z, so.z, py, xprev, true); xprev = Xi.z; \
            lif_step(Xi.w, decay, v, u, vo.w, so.w, pz, xprev, true); xprev = Xi.w; \
            if (s0 && s1) vo.z = VTH;   /* counter==2 corner: spikes at t=0 and t=1 */ \
            close = 0.0f;                                                      \
        } else {                                                               \
            group4(Xi, decay, v, u, xprev, vo, so, close, px, py, pz);         \
        }                                                                      \
        if (gi >= wg) {                                                        \
            v4[m] = vo; s4[m] = so;                                            \
            if (gi > wg) { pend.w = close; d4[m - 1] = pend; }                 \
            pend.x = px; pend.y = py; pend.z = pz;                             \
        }                                                                      \
        if (gi == wg - 1) Sst[k * B + b] = make_float2(v, u);                  \
        if (gi + 8 < ng) Xi = x4[m + 8];                                       \
    }

    for (int gg = 0; gg < ng; gg += 8) {
        STAGE(0, X0) STAGE(1, X1) STAGE(2, X2) STAGE(3, X3)
        STAGE(4, X4v) STAGE(5, X5) STAGE(6, X6) STAGE(7, X7)
    }
#undef STAGE

    Est[k * B + b] = make_float2(v, u);    // exit state BEFORE lookahead mutates v,u

    // lookahead: finalize dv[(k+1)L - 1]
    float closeLA;
    if (k < K - 1) {
        float xla = ode[bt + (size_t)(k + 1) * L];
        float vo_, so_;
        lif_step(xla, decay, v, u, vo_, so_, closeLA, xprev, true);
    } else {
        closeLA = (u > 1.0f) ? 0.0f : xprev;   // dv[T-1]
    }
    pend.w = closeLA;
    d4[m0 + ng - 1] = pend;
}

// ---------------- exact re-run of one chunk from a given entry state ----------------
__device__ void rerun_chunk(int k, float2& st, const float* __restrict__ ode, float decay,
                            float* vout, float* sout, float* dvout, int b) {
    const size_t bt = (size_t)b * T;
    const float4* __restrict__ x4 = (const float4*)(ode + bt);
    float4* v4 = (float4*)(vout + bt);
    float4* s4 = (float4*)(sout + bt);
    float4* d4 = (float4*)(dvout + bt);
    const int m0 = k * LG;

    float v = st.x, u = st.y, xprev = 0.0f;
    float4 pend;
    for (int c = 0; c < LG; ++c) {
        float4 X = x4[m0 + c];
        float4 vo, so; float close, px, py, pz;
        group4(X, decay, v, u, xprev, vo, so, close, px, py, pz);
        v4[m0 + c] = vo; s4[m0 + c] = so;
        if (c > 0) { pend.w = close; d4[m0 + c - 1] = pend; }
        pend.x = px; pend.y = py; pend.z = pz;
    }
    st = make_float2(v, u);                // corrected exit state
    float close;
    if (k < K - 1) {
        float xla = ode[bt + (size_t)(k + 1) * L];
        float vo_, so_;
        lif_step(xla, decay, v, u, vo_, so_, close, xprev, true);
    } else {
        close = (u > 1.0f) ? 0.0f : xprev;
    }
    pend.w = close;
    d4[m0 + LG - 1] = pend;
}

// ---------------- verify + (rare) repair ----------------
__global__ __launch_bounds__(64, 1)
void lif_fix(const float* __restrict__ ode, const float* __restrict__ decay_p,
             float* vout, float* sout, float* dvout,
             const float2* __restrict__ Sst, const float2* __restrict__ Est, int B) {
    const int b = blockIdx.x * 64 + threadIdx.x;
    if (b >= B) return;

    // fast check: all boundary states consistent? (loads pipelined by unroll)
    bool ok = true;
    float2 ep = Est[b];
    #pragma unroll
    for (int k = 1; k < K; ++k) {
        float2 sk = Sst[k * B + b];
        float2 ek = Est[k * B + b];
        ok &= (sk.x == ep.x) & (sk.y == ep.y);
        ep = ek;
    }
    if (ok) return;

    // slow path: sequential walk with chunk-granular repair (exact by induction)
    const float decay = decay_p[0];
    float2 cur = Est[b];                   // E_0 is exact (chunk 0 has no warm-up)
    for (int k = 1; k < K; ++k) {
        float2 sk = Sst[k * B + b];
        if (sk.x == cur.x && sk.y == cur.y) {
            cur = Est[k * B + b];          // spec outputs for chunk k are exact
        } else {
            rerun_chunk(k, cur, ode, decay, vout, sout, dvout, b);
        }
    }
}

extern "C" void kernel_launch(void* const* d_in, const int* in_sizes, int n_in,
                              void* d_out, int out_size, void* d_ws, size_t ws_size,
                              hipStream_t stream) {
    const float* ode   = (const float*)d_in[0];
    const float* decay = (const float*)d_in[1];
    float* out = (float*)d_out;

    const int BT = in_sizes[0];            // B*T
    const int B  = BT / T;                 // 2048

    float* vout  = out;
    float* sout  = out + (size_t)BT;
    float* dvout = out + 2 * (size_t)BT;

    float2* Sst = (float2*)d_ws;           // [K][B]
    float2* Est = Sst + (size_t)K * B;     // [K][B]  (1 MB total, << ws_size)

    lif_spec<<<dim3((B * K) / 64), dim3(64), 0, stream>>>(ode, decay, vout, sout, dvout,
                                                          Sst, Est, B);
    lif_fix<<<dim3((B + 63) / 64), dim3(64), 0, stream>>>(ode, decay, vout, sout, dvout,
                                                          Sst, Est, B);
}

// Round 4
// 286.682 us; speedup vs baseline: 1.5466x; 1.5466x over previous
//
#include <hip/hip_runtime.h>

constexpr int   T   = 4096;
constexpr float VTH = 1.27f;
constexpr int   K   = 64;        // time chunks per row
constexpr int   L   = T / K;     // 64 steps per chunk
constexpr int   LG  = L / 4;     // 16 float4 groups per chunk

// Full LIF step (bit-exact vs reference; validated absmax 0.0 in R2/R3).
// v: membrane (0 carried out of a spike step); u: countdown (7 after spike, via setu).
//   x zeroed this step iff u_entry >= 3 ; dv[t-1] zeroed iff u_exit > 0
__device__ __forceinline__ bool lif_step(float x, float decay, float& v, float& u,
                                         float& vo, float& so, float& dvo, float xprev) {
    float t1 = __fmul_rn(decay, v);
    float vd = __fsub_rn(v, t1);           // unfused — matches reference rounding
    float xe = (u >= 3.0f) ? 0.0f : x;
    float vn = __fadd_rn(vd, xe);
    bool  s  = vn > VTH;
    vo = s ? VTH  : vn;
    so = s ? 1.0f : 0.0f;
    v  = s ? 0.0f : vn;
    float us = s ? 8.0f : u;
    u = fmaxf(us - 1.0f, 0.0f);
    dvo = (u > 0.0f) ? 0.0f : xprev;
    return s;
}

// State-only step (Phase A): same arithmetic, no outputs.
__device__ __forceinline__ bool state_step(float x, float decay, float& v, float& u) {
    float t1 = __fmul_rn(decay, v);
    float vd = __fsub_rn(v, t1);
    float xe = (u >= 3.0f) ? 0.0f : x;
    float vn = __fadd_rn(vd, xe);
    bool  s  = vn > VTH;
    v = s ? 0.0f : vn;
    float us = s ? 8.0f : u;
    u = fmaxf(us - 1.0f, 0.0f);
    return s;
}

// 4 full steps. close = dv[t-1]; px,py,pz = dv[t..t+2].
__device__ __forceinline__ void group4(float4 X, float decay, float& v, float& u,
                                       float& xprev, float4& vo, float4& so,
                                       float& close, float& px, float& py, float& pz) {
    lif_step(X.x, decay, v, u, vo.x, so.x, close, xprev); xprev = X.x;
    lif_step(X.y, decay, v, u, vo.y, so.y, px,    xprev); xprev = X.y;
    lif_step(X.z, decay, v, u, vo.z, so.z, py,    xprev); xprev = X.z;
    lif_step(X.w, decay, v, u, vo.w, so.w, pz,    xprev); xprev = X.w;
}

// ---------------- Phase A: exact boundary states, 1 thread/row ----------------
__global__ __launch_bounds__(64, 1)
void lif_states(const float* __restrict__ ode, const float* __restrict__ decay_p,
                float2* __restrict__ Sb, int B) {
    const int b = blockIdx.x * 64 + threadIdx.x;
    const float decay = decay_p[0];
    const float4* __restrict__ x4 = (const float4*)(ode + (size_t)b * T);

    constexpr int NGA = (T - L) / 4;   // 1008 groups = 4032 steps (last chunk entry)

    float v = 0.0f, u = 0.0f;

    // 16-deep named-register prefetch ring (~1280 cyc lookahead)
    float4 Q0 = x4[0],  Q1 = x4[1],  Q2 = x4[2],  Q3 = x4[3];
    float4 Q4 = x4[4],  Q5 = x4[5],  Q6 = x4[6],  Q7 = x4[7];
    float4 Q8 = x4[8],  Q9 = x4[9],  Q10 = x4[10], Q11 = x4[11];
    float4 Q12 = x4[12], Q13 = x4[13], Q14 = x4[14], Q15 = x4[15];

#define ASG(i, Qi)                                                        \
    {                                                                     \
        state_step(Qi.x, decay, v, u); state_step(Qi.y, decay, v, u);     \
        state_step(Qi.z, decay, v, u); state_step(Qi.w, decay, v, u);     \
        int ridx = base + (i) + 16; ridx = ridx < NGA ? ridx : NGA - 1;   \
        Qi = x4[ridx];                                                    \
    }

    // super-group 0: step 0 special (t=0 spike does NOT arm the window)
    {
        const int base = 0;
        {
            bool s0 = state_step(Q0.x, decay, v, u);
            if (s0) u = 0.0f;                       // undo arming for t=0
            state_step(Q0.y, decay, v, u);
            state_step(Q0.z, decay, v, u);
            state_step(Q0.w, decay, v, u);
            Q0 = x4[16];
        }
        ASG(1, Q1)  ASG(2, Q2)  ASG(3, Q3)
        ASG(4, Q4)  ASG(5, Q5)  ASG(6, Q6)  ASG(7, Q7)
        ASG(8, Q8)  ASG(9, Q9)  ASG(10, Q10) ASG(11, Q11)
        ASG(12, Q12) ASG(13, Q13) ASG(14, Q14) ASG(15, Q15)
        Sb[1 * B + b] = make_float2(v, u);          // entry state of chunk 1
    }

    for (int sg = 1; sg < 63; ++sg) {
        const int base = sg * 16;
        ASG(0, Q0)  ASG(1, Q1)  ASG(2, Q2)  ASG(3, Q3)
        ASG(4, Q4)  ASG(5, Q5)  ASG(6, Q6)  ASG(7, Q7)
        ASG(8, Q8)  ASG(9, Q9)  ASG(10, Q10) ASG(11, Q11)
        ASG(12, Q12) ASG(13, Q13) ASG(14, Q14) ASG(15, Q15)
        Sb[(sg + 1) * B + b] = make_float2(v, u);   // entry state of chunk sg+1
    }
#undef ASG
}

// ---------------- Phase B: one chunk per thread, exact entry, all outputs ----------------
__global__ __launch_bounds__(256, 2)
void lif_out(const float* __restrict__ ode, const float* __restrict__ decay_p,
             float* __restrict__ vout, float* __restrict__ sout,
             float* __restrict__ dvout, const float2* __restrict__ Sb, int B) {
    const int lane = threadIdx.x & 63;
    const int wid  = threadIdx.x >> 6;
    const int task = blockIdx.x * 4 + wid;   // 0 .. (B/64)*K - 1
    const int rg   = task >> 6;              // row group (task / K), K==64
    const int k    = task & 63;              // chunk    (task % K)
    const int b    = rg * 64 + lane;
    const float decay = decay_p[0];

    const size_t bt = (size_t)b * T;
    const int g0 = k * LG;                   // first float4 group of this chunk
    const float4* __restrict__ x4 = (const float4*)(ode + bt);
    float4* __restrict__ v4 = (float4*)(vout + bt);
    float4* __restrict__ s4 = (float4*)(sout + bt);
    float4* __restrict__ d4 = (float4*)(dvout + bt);

    float v, u;
    if (k == 0) { v = 0.0f; u = 0.0f; }
    else        { float2 st = Sb[k * B + b]; v = st.x; u = st.y; }

    // prefetch lookahead scalar early (finalizes dv[t0+L-1])
    float xla = (k < K - 1) ? ode[bt + (size_t)(k + 1) * L] : 0.0f;

    float xprev = 0.0f;
    float4 pend;

    float4 X0 = x4[g0], X1 = x4[g0 + 1], X2 = x4[g0 + 2], X3 = x4[g0 + 3];

    // group 0: produces pend.xyz = dv[t0..t0+2]; its 'close' (dv[t0-1]) is owned
    // by chunk k-1's lookahead and discarded here.
    {
        float4 vo, so; float close, px, py, pz;
        if (k == 0) {
            float dvd;
            bool s0 = lif_step(X0.x, decay, v, u, vo.x, so.x, dvd, xprev);
            if (s0) u = 0.0f;                // t=0 spike doesn't arm the window
            xprev = X0.x;
            bool s1 = lif_step(X0.y, decay, v, u, vo.y, so.y, px, xprev); xprev = X0.y;
            lif_step(X0.z, decay, v, u, vo.z, so.z, py, xprev); xprev = X0.z;
            lif_step(X0.w, decay, v, u, vo.w, so.w, pz, xprev); xprev = X0.w;
            if (s0 && s1) vo.z = VTH;        // counter==2 corner: spikes at t=0 and t=1
        } else {
            group4(X0, decay, v, u, xprev, vo, so, close, px, py, pz);
        }
        v4[g0] = vo; s4[g0] = so;
        pend.x = px; pend.y = py; pend.z = pz;
        X0 = x4[g0 + 4];
    }

#define BSTAGE(c, Xi)                                                     \
    {                                                                     \
        float4 vo, so; float close, px, py, pz;                           \
        group4(Xi, decay, v, u, xprev, vo, so, close, px, py, pz);        \
        pend.w = close; d4[g0 + (c) - 1] = pend;                          \
        pend.x = px; pend.y = py; pend.z = pz;                            \
        v4[g0 + (c)] = vo; s4[g0 + (c)] = so;                             \
        if ((c) + 4 < LG) Xi = x4[g0 + (c) + 4];                          \
    }
    BSTAGE(1, X1)  BSTAGE(2, X2)  BSTAGE(3, X3)
    BSTAGE(4, X0)  BSTAGE(5, X1)  BSTAGE(6, X2)  BSTAGE(7, X3)
    BSTAGE(8, X0)  BSTAGE(9, X1)  BSTAGE(10, X2) BSTAGE(11, X3)
    BSTAGE(12, X0) BSTAGE(13, X1) BSTAGE(14, X2) BSTAGE(15, X3)
#undef BSTAGE

    // finalize dv[t0+L-1]
    float closeLA;
    if (k < K - 1) {
        float vo_, so_, dum = 0.0f;
        (void)dum;
        lif_step(xla, decay, v, u, vo_, so_, closeLA, xprev);
    } else {
        closeLA = (u > 1.0f) ? 0.0f : xprev;   // dv[T-1]: zero iff last spike >= T-6
    }
    pend.w = closeLA;
    d4[g0 + LG - 1] = pend;
}

extern "C" void kernel_launch(void* const* d_in, const int* in_sizes, int n_in,
                              void* d_out, int out_size, void* d_ws, size_t ws_size,
                              hipStream_t stream) {
    const float* ode   = (const float*)d_in[0];
    const float* decay = (const float*)d_in[1];
    float* out = (float*)d_out;

    const int BT = in_sizes[0];            // B*T
    const int B  = BT / T;                 // 2048

    float* vout  = out;
    float* sout  = out + (size_t)BT;
    float* dvout = out + 2 * (size_t)BT;

    float2* Sb = (float2*)d_ws;            // [K][B] boundary entry states (1 MB)

    lif_states<<<dim3(B / 64), dim3(64), 0, stream>>>(ode, decay, Sb, B);

    const int tasks = (B / 64) * K;        // 2048 wave-tasks
    lif_out<<<dim3(tasks / 4), dim3(256), 0, stream>>>(ode, decay, vout, sout, dvout, Sb, B);
}

// Round 5
// 281.822 us; speedup vs baseline: 1.5732x; 1.0172x over previous
//
#include <hip/hip_runtime.h>

constexpr int   T   = 4096;
constexpr float VTH = 1.27f;
constexpr int   K   = 64;        // time chunks per row
constexpr int   L   = T / K;     // 64 steps per chunk
constexpr int   LG  = L / 4;     // 16 float4 groups per chunk

// ---- h-mask LIF step: bitwise-equal to the validated float-u machine (R2/R4 absmax 0.0).
// h: spike history, bit j == spike at (t-1-j). gate (carried) == spike in [t-5, t-1].
// Gated xe = exact 0.0f so vn matches __fadd_rn(vd, 0) == vd (vd = -0 unreachable: v decays
// <=5 gated steps between input adds, no denormal path).
__device__ __forceinline__ bool sstep(float x, float decay, float& v, unsigned& h, bool& gate) {
    float t1 = __fmul_rn(decay, v);
    float vd = __fsub_rn(v, t1);           // unfused — matches reference rounding
    float xe = gate ? 0.0f : x;
    float vn = __fadd_rn(vd, xe);
    bool  s  = vn > VTH;
    v = s ? 0.0f : vn;
    bool g4 = (h & 15u) != 0u;             // spikes t-1..t-4 (pre-shift)
    h = (h << 1) | (s ? 1u : 0u);
    gate = s || g4;                         // spike in [t-4, t] == gate for step t+1
    return s;
}

// Full step with outputs: vo, so for step t; dvo = dv[t-1] (zero iff spike in [t-6, t]).
__device__ __forceinline__ bool ostep(float x, float decay, float& v, unsigned& h, bool& gate,
                                      float& vo, float& so, float& dvo, float xprev) {
    float t1 = __fmul_rn(decay, v);
    float vd = __fsub_rn(v, t1);
    float xe = gate ? 0.0f : x;
    float vn = __fadd_rn(vd, xe);
    bool  s  = vn > VTH;
    vo = s ? VTH  : vn;
    so = s ? 1.0f : 0.0f;
    v  = s ? 0.0f : vn;
    bool z6 = s || ((h & 63u) != 0u);      // spike in [t-6, t]
    dvo = z6 ? 0.0f : xprev;
    bool g4 = (h & 15u) != 0u;
    h = (h << 1) | (s ? 1u : 0u);
    gate = s || g4;
    return s;
}

// 4 full steps: close = dv[t-1]; px,py,pz = dv[t..t+2].
__device__ __forceinline__ void ogroup(float4 X, float decay, float& v, unsigned& h, bool& gate,
                                       float& xprev, float4& vo, float4& so,
                                       float& close, float& px, float& py, float& pz) {
    ostep(X.x, decay, v, h, gate, vo.x, so.x, close, xprev); xprev = X.x;
    ostep(X.y, decay, v, h, gate, vo.y, so.y, px,    xprev); xprev = X.y;
    ostep(X.z, decay, v, h, gate, vo.z, so.z, py,    xprev); xprev = X.z;
    ostep(X.w, decay, v, h, gate, vo.w, so.w, pz,    xprev); xprev = X.w;
}

// ---------------- Phase A: exact boundary states, 1 thread/row ----------------
__global__ __launch_bounds__(64, 1)
void lif_states(const float* __restrict__ ode, const float* __restrict__ decay_p,
                float2* __restrict__ Sb, int B) {
    const int b = blockIdx.x * 64 + threadIdx.x;
    const float decay = decay_p[0];
    const float4* __restrict__ x4 = (const float4*)(ode + (size_t)b * T);

    float v = 0.0f; unsigned h = 0u; bool gate = false;

    // 16-deep named-register prefetch ring
    float4 Q0 = x4[0],  Q1 = x4[1],  Q2 = x4[2],  Q3 = x4[3];
    float4 Q4 = x4[4],  Q5 = x4[5],  Q6 = x4[6],  Q7 = x4[7];
    float4 Q8 = x4[8],  Q9 = x4[9],  Q10 = x4[10], Q11 = x4[11];
    float4 Q12 = x4[12], Q13 = x4[13], Q14 = x4[14], Q15 = x4[15];

#define ASG(i, Qi)                                                        \
    {                                                                     \
        sstep(Qi.x, decay, v, h, gate); sstep(Qi.y, decay, v, h, gate);   \
        sstep(Qi.z, decay, v, h, gate); sstep(Qi.w, decay, v, h, gate);   \
        Qi = x4[base + (i) + 16];                                         \
    }

    { // super-group 0: step 0 special (t=0 spike does NOT arm the window)
        const int base = 0;
        {
            sstep(Q0.x, decay, v, h, gate);
            h = 0u; gate = false;                  // cancel arming for t=0
            sstep(Q0.y, decay, v, h, gate);
            sstep(Q0.z, decay, v, h, gate);
            sstep(Q0.w, decay, v, h, gate);
            Q0 = x4[16];
        }
        ASG(1, Q1)  ASG(2, Q2)  ASG(3, Q3)
        ASG(4, Q4)  ASG(5, Q5)  ASG(6, Q6)  ASG(7, Q7)
        ASG(8, Q8)  ASG(9, Q9)  ASG(10, Q10) ASG(11, Q11)
        ASG(12, Q12) ASG(13, Q13) ASG(14, Q14) ASG(15, Q15)
        Sb[1 * B + b] = make_float2(v, __uint_as_float(h & 127u));
    }
#pragma unroll 1
    for (int sg = 1; sg < 63; ++sg) {              // max reload idx 992+15+16 = 1023 < 1024
        const int base = sg * 16;
        ASG(0, Q0)  ASG(1, Q1)  ASG(2, Q2)  ASG(3, Q3)
        ASG(4, Q4)  ASG(5, Q5)  ASG(6, Q6)  ASG(7, Q7)
        ASG(8, Q8)  ASG(9, Q9)  ASG(10, Q10) ASG(11, Q11)
        ASG(12, Q12) ASG(13, Q13) ASG(14, Q14) ASG(15, Q15)
        Sb[(sg + 1) * B + b] = make_float2(v, __uint_as_float(h & 127u));
    }
#undef ASG
}

// ---------------- Phase B: one chunk per thread, register-tiled burst stores ----------------
__global__ __launch_bounds__(256, 2)
void lif_out(const float* __restrict__ ode, const float* __restrict__ decay_p,
             float* __restrict__ vout, float* __restrict__ sout,
             float* __restrict__ dvout, const float2* __restrict__ Sb, int B) {
    const int lane = threadIdx.x & 63;
    const int wid  = threadIdx.x >> 6;
    const int task = blockIdx.x * 4 + wid;   // 0 .. (B/64)*K - 1
    const int rg   = task >> 6;              // row group (task / K), K==64
    const int k    = task & 63;              // chunk    (task % K)
    const int b    = rg * 64 + lane;
    const float decay = decay_p[0];

    const size_t bt = (size_t)b * T;
    const int g0 = k * LG;
    const float4* __restrict__ x4 = (const float4*)(ode + bt);
    float4* __restrict__ v4 = (float4*)(vout + bt);
    float4* __restrict__ s4 = (float4*)(sout + bt);
    float4* __restrict__ d4 = (float4*)(dvout + bt);

    float v; unsigned h;
    if (k == 0) { v = 0.0f; h = 0u; }
    else        { float2 st = Sb[k * B + b]; v = st.x; h = __float_as_uint(st.y); }
    bool gate = (h & 31u) != 0u;

    float xla = (k < K - 1) ? ode[bt + (size_t)(k + 1) * L] : 0.0f;

    float xprev = 0.0f, cl;
    float4 X0 = x4[g0], X1 = x4[g0 + 1], X2 = x4[g0 + 2], X3 = x4[g0 + 3];
    float4 V0, V1, V2, V3, S0, S1, S2, S3;
    float4 DA0, DA1, DA2, DA3, DB0, DB1, DB2, DB3;

    // ---------- quad 0 (groups 0..3) ----------
    if (k == 0) {  // t=0 special + counter==2 corner
        bool s0 = ostep(X0.x, decay, v, h, gate, V0.x, S0.x, cl, xprev); xprev = X0.x;
        h = 0u; gate = false;                // t=0 spike doesn't arm the window
        bool s1 = ostep(X0.y, decay, v, h, gate, V0.y, S0.y, DA0.x, xprev); xprev = X0.y;
        ostep(X0.z, decay, v, h, gate, V0.z, S0.z, DA0.y, xprev); xprev = X0.z;
        ostep(X0.w, decay, v, h, gate, V0.w, S0.w, DA0.z, xprev); xprev = X0.w;
        if (s0 && s1) V0.z = VTH;            // spikes at t=0 and t=1 force v_rec[2]=VTH
    } else {
        ogroup(X0, decay, v, h, gate, xprev, V0, S0, cl, DA0.x, DA0.y, DA0.z); // cl: prev chunk owns dv[t0-1]
    }
    X0 = x4[g0 + 4];
    ogroup(X1, decay, v, h, gate, xprev, V1, S1, DA0.w, DA1.x, DA1.y, DA1.z); X1 = x4[g0 + 5];
    ogroup(X2, decay, v, h, gate, xprev, V2, S2, DA1.w, DA2.x, DA2.y, DA2.z); X2 = x4[g0 + 6];
    ogroup(X3, decay, v, h, gate, xprev, V3, S3, DA2.w, DA3.x, DA3.y, DA3.z); X3 = x4[g0 + 7];
    v4[g0 + 0] = V0; v4[g0 + 1] = V1; v4[g0 + 2] = V2; v4[g0 + 3] = V3;   // full-line burst
    s4[g0 + 0] = S0; s4[g0 + 1] = S1; s4[g0 + 2] = S2; s4[g0 + 3] = S3;

    // ---------- quad 1 (groups 4..7) ----------
    ogroup(X0, decay, v, h, gate, xprev, V0, S0, DA3.w, DB0.x, DB0.y, DB0.z); X0 = x4[g0 + 8];
    d4[g0 + 0] = DA0; d4[g0 + 1] = DA1; d4[g0 + 2] = DA2; d4[g0 + 3] = DA3;
    ogroup(X1, decay, v, h, gate, xprev, V1, S1, DB0.w, DB1.x, DB1.y, DB1.z); X1 = x4[g0 + 9];
    ogroup(X2, decay, v, h, gate, xprev, V2, S2, DB1.w, DB2.x, DB2.y, DB2.z); X2 = x4[g0 + 10];
    ogroup(X3, decay, v, h, gate, xprev, V3, S3, DB2.w, DB3.x, DB3.y, DB3.z); X3 = x4[g0 + 11];
    v4[g0 + 4] = V0; v4[g0 + 5] = V1; v4[g0 + 6] = V2; v4[g0 + 7] = V3;
    s4[g0 + 4] = S0; s4[g0 + 5] = S1; s4[g0 + 6] = S2; s4[g0 + 7] = S3;

    // ---------- quad 2 (groups 8..11) ----------
    ogroup(X0, decay, v, h, gate, xprev, V0, S0, DB3.w, DA0.x, DA0.y, DA0.z); X0 = x4[g0 + 12];
    d4[g0 + 4] = DB0; d4[g0 + 5] = DB1; d4[g0 + 6] = DB2; d4[g0 + 7] = DB3;
    ogroup(X1, decay, v, h, gate, xprev, V1, S1, DA0.w, DA1.x, DA1.y, DA1.z); X1 = x4[g0 + 13];
    ogroup(X2, decay, v, h, gate, xprev, V2, S2, DA1.w, DA2.x, DA2.y, DA2.z); X2 = x4[g0 + 14];
    ogroup(X3, decay, v, h, gate, xprev, V3, S3, DA2.w, DA3.x, DA3.y, DA3.z); X3 = x4[g0 + 15];
    v4[g0 + 8] = V0; v4[g0 + 9] = V1; v4[g0 + 10] = V2; v4[g0 + 11] = V3;
    s4[g0 + 8] = S0; s4[g0 + 9] = S1; s4[g0 + 10] = S2; s4[g0 + 11] = S3;

    // ---------- quad 3 (groups 12..15) ----------
    ogroup(X0, decay, v, h, gate, xprev, V0, S0, DA3.w, DB0.x, DB0.y, DB0.z);
    d4[g0 + 8] = DA0; d4[g0 + 9] = DA1; d4[g0 + 10] = DA2; d4[g0 + 11] = DA3;
    ogroup(X1, decay, v, h, gate, xprev, V1, S1, DB0.w, DB1.x, DB1.y, DB1.z);
    ogroup(X2, decay, v, h, gate, xprev, V2, S2, DB1.w, DB2.x, DB2.y, DB2.z);
    ogroup(X3, decay, v, h, gate, xprev, V3, S3, DB2.w, DB3.x, DB3.y, DB3.z);
    v4[g0 + 12] = V0; v4[g0 + 13] = V1; v4[g0 + 14] = V2; v4[g0 + 15] = V3;
    s4[g0 + 12] = S0; s4[g0 + 13] = S1; s4[g0 + 14] = S2; s4[g0 + 15] = S3;

    // lookahead closes dv[t0+L-1]
    if (k < K - 1) {
        float vo_, so_;
        ostep(xla, decay, v, h, gate, vo_, so_, DB3.w, xprev);
    } else {
        DB3.w = ((h & 63u) != 0u) ? 0.0f : xprev;   // dv[T-1]: zero iff spike in [T-6, T-1]
    }
    d4[g0 + 12] = DB0; d4[g0 + 13] = DB1; d4[g0 + 14] = DB2; d4[g0 + 15] = DB3;
}

extern "C" void kernel_launch(void* const* d_in, const int* in_sizes, int n_in,
                              void* d_out, int out_size, void* d_ws, size_t ws_size,
                              hipStream_t stream) {
    const float* ode   = (const float*)d_in[0];
    const float* decay = (const float*)d_in[1];
    float* out = (float*)d_out;

    const int BT = in_sizes[0];            // B*T
    const int B  = BT / T;                 // 2048

    float* vout  = out;
    float* sout  = out + (size_t)BT;
    float* dvout = out + 2 * (size_t)BT;

    float2* Sb = (float2*)d_ws;            // [K][B] boundary states (v, h-bits), 1 MB

    lif_states<<<dim3(B / 64), dim3(64), 0, stream>>>(ode, decay, Sb, B);

    const int tasks = (B / 64) * K;        // 2048 wave-tasks
    lif_out<<<dim3(tasks / 4), dim3(256), 0, stream>>>(ode, decay, vout, sout, dvout, Sb, B);
}

// Round 6
// 238.172 us; speedup vs baseline: 1.8616x; 1.1833x over previous
//
#include <hip/hip_runtime.h>

constexpr int   T   = 4096;
constexpr float VTH = 1.27f;
constexpr int   K   = 16;         // time chunks per row
constexpr int   L   = T / K;      // 256 steps per chunk
constexpr int   LG  = L / 4;      // 64 float4 groups per chunk
constexpr int   WG  = 128;        // warm-up groups = 512 steps (lock fail ~0.3%/boundary @ measured hazard 1.14%/step)

// ---- h-mask LIF machine (bitwise-validated vs reference: absmax 0.0 in R5) ----
// h bit j == spike at (t-1-j). gate (carried) == spike in [t-5, t-1].
__device__ __forceinline__ bool sstep(float x, float decay, float& v, unsigned& h, bool& gate) {
    float t1 = __fmul_rn(decay, v);
    float vd = __fsub_rn(v, t1);           // unfused — matches reference rounding
    float xe = gate ? 0.0f : x;
    float vn = __fadd_rn(vd, xe);
    bool  s  = vn > VTH;
    v = s ? 0.0f : vn;
    bool g4 = (h & 15u) != 0u;
    h = (h << 1) | (s ? 1u : 0u);
    gate = s || g4;
    return s;
}

// vo, so for step t; dvo = dv[t-1] (zero iff spike in [t-6, t]).
__device__ __forceinline__ bool ostep(float x, float decay, float& v, unsigned& h, bool& gate,
                                      float& vo, float& so, float& dvo, float xprev) {
    float t1 = __fmul_rn(decay, v);
    float vd = __fsub_rn(v, t1);
    float xe = gate ? 0.0f : x;
    float vn = __fadd_rn(vd, xe);
    bool  s  = vn > VTH;
    vo = s ? VTH  : vn;
    so = s ? 1.0f : 0.0f;
    v  = s ? 0.0f : vn;
    bool z6 = s || ((h & 63u) != 0u);
    dvo = z6 ? 0.0f : xprev;
    bool g4 = (h & 15u) != 0u;
    h = (h << 1) | (s ? 1u : 0u);
    gate = s || g4;
    return s;
}

__device__ __forceinline__ void ogroup(float4 X, float decay, float& v, unsigned& h, bool& gate,
                                       float& xprev, float4& vo, float4& so,
                                       float& close, float& px, float& py, float& pz) {
    ostep(X.x, decay, v, h, gate, vo.x, so.x, close, xprev); xprev = X.x;
    ostep(X.y, decay, v, h, gate, vo.y, so.y, px,    xprev); xprev = X.y;
    ostep(X.z, decay, v, h, gate, vo.z, so.z, py,    xprev); xprev = X.z;
    ostep(X.w, decay, v, h, gate, vo.w, so.w, pz,    xprev); xprev = X.w;
}

// Quad q (groups 4q..4q+3): v/s bursts; fills D0..3 (dv of this quad) except D3.w;
// its first close completes P3.w and flushes P0..3 (dv of quad q-1). q>=1.
__device__ __forceinline__ void quad_run(int q, const float4* __restrict__ x4, int g0f,
        float decay, float& v, unsigned& h, bool& gate, float& xprev,
        float4& Xa, float4& Xb, float4& Xc, float4& Xd,
        float4& D0, float4& D1, float4& D2, float4& D3,
        float4& P0, float4& P1, float4& P2, float4& P3,
        float4* __restrict__ v4, float4* __restrict__ s4, float4* __restrict__ d4) {
    float4 V0, V1, V2, V3, S0, S1, S2, S3;
    ogroup(Xa, decay, v, h, gate, xprev, V0, S0, P3.w, D0.x, D0.y, D0.z);
    Xa = x4[g0f + (4*q + 4 < LG ? 4*q + 4 : LG - 1)];
    d4[g0f + 4*q - 4] = P0; d4[g0f + 4*q - 3] = P1;
    d4[g0f + 4*q - 2] = P2; d4[g0f + 4*q - 1] = P3;
    ogroup(Xb, decay, v, h, gate, xprev, V1, S1, D0.w, D1.x, D1.y, D1.z);
    Xb = x4[g0f + (4*q + 5 < LG ? 4*q + 5 : LG - 1)];
    ogroup(Xc, decay, v, h, gate, xprev, V2, S2, D1.w, D2.x, D2.y, D2.z);
    Xc = x4[g0f + (4*q + 6 < LG ? 4*q + 6 : LG - 1)];
    ogroup(Xd, decay, v, h, gate, xprev, V3, S3, D2.w, D3.x, D3.y, D3.z);
    Xd = x4[g0f + (4*q + 7 < LG ? 4*q + 7 : LG - 1)];
    v4[g0f + 4*q] = V0; v4[g0f + 4*q + 1] = V1; v4[g0f + 4*q + 2] = V2; v4[g0f + 4*q + 3] = V3;
    s4[g0f + 4*q] = S0; s4[g0f + 4*q + 1] = S1; s4[g0f + 4*q + 2] = S2; s4[g0f + 4*q + 3] = S3;
}

// ---------------- fused speculative chunk kernel ----------------
__global__ __launch_bounds__(64, 1)
void lif_spec(const float* __restrict__ ode, const float* __restrict__ decay_p,
              float* __restrict__ vout, float* __restrict__ sout, float* __restrict__ dvout,
              float2* __restrict__ Sst, float2* __restrict__ Est, int B) {
    const int g = blockIdx.x * 64 + threadIdx.x;
    const int b = g % B;                  // consecutive lanes = consecutive rows
    const int k = g / B;                  // wave-uniform chunk id
    const float decay = decay_p[0];

    const size_t bt = (size_t)b * T;
    const float4* __restrict__ x4 = (const float4*)(ode + bt);
    float4* __restrict__ v4 = (float4*)(vout + bt);
    float4* __restrict__ s4 = (float4*)(sout + bt);
    float4* __restrict__ d4 = (float4*)(dvout + bt);

    const int g0f = k * LG;
    const int wg  = (k == 0) ? 0 : (k * LG < WG ? k * LG : WG);   // 0 / 64 / 128
    float v = 0.0f; unsigned h = 0u; bool gate = false;
    float xprev = 0.0f;

    // ---- warm-up (state only). Chunks 1,2 cover the full prefix -> exact.
    if (wg > 0) {
        const float4* __restrict__ xw = x4 + (g0f - wg);
        const bool t0row = (g0f - wg == 0);
        float4 Q0 = xw[0], Q1 = xw[1], Q2 = xw[2], Q3 = xw[3];
        float4 Q4 = xw[4], Q5 = xw[5], Q6 = xw[6], Q7 = xw[7];
#define WSG(i, Qi)                                                            \
        { sstep(Qi.x, decay, v, h, gate); sstep(Qi.y, decay, v, h, gate);     \
          sstep(Qi.z, decay, v, h, gate); sstep(Qi.w, decay, v, h, gate);     \
          Qi = xw[c + (i) + 8]; }
        for (int c = 0; c < wg; c += 8) {
            if (c == 0 && t0row) {        // t=0 spike does NOT arm the window
                sstep(Q0.x, decay, v, h, gate); h = 0u; gate = false;
                sstep(Q0.y, decay, v, h, gate);
                sstep(Q0.z, decay, v, h, gate);
                sstep(Q0.w, decay, v, h, gate);
                Q0 = xw[8];
            } else { WSG(0, Q0) }
            WSG(1, Q1) WSG(2, Q2) WSG(3, Q3)
            WSG(4, Q4) WSG(5, Q5) WSG(6, Q6) WSG(7, Q7)
        }
#undef WSG
        Sst[k * B + b] = make_float2(v, __uint_as_float(h & 127u));
    }

    // ---- main: 16 quads with burst stores (R5-validated dv ownership:
    // first close of the chunk is dv[t0-1], owned by chunk k-1's lookahead)
    float xla = (k < K - 1) ? ode[bt + (size_t)(k + 1) * L] : 0.0f;
    float4 Xa = x4[g0f], Xb = x4[g0f + 1], Xc = x4[g0f + 2], Xd = x4[g0f + 3];
    float4 DA0, DA1, DA2, DA3, DB0, DB1, DB2, DB3;

    {   // quad 0
        float4 V0, V1, V2, V3, S0, S1, S2, S3;
        if (k == 0) {
            float dvd;
            bool s0 = ostep(Xa.x, decay, v, h, gate, V0.x, S0.x, dvd, xprev); xprev = Xa.x;
            h = 0u; gate = false;          // t=0 spike doesn't arm the window
            bool s1 = ostep(Xa.y, decay, v, h, gate, V0.y, S0.y, DA0.x, xprev); xprev = Xa.y;
            ostep(Xa.z, decay, v, h, gate, V0.z, S0.z, DA0.y, xprev); xprev = Xa.z;
            ostep(Xa.w, decay, v, h, gate, V0.w, S0.w, DA0.z, xprev); xprev = Xa.w;
            if (s0 && s1) V0.z = VTH;      // counter==2 corner: spikes at t=0 and t=1
        } else {
            float cl;
            ogroup(Xa, decay, v, h, gate, xprev, V0, S0, cl, DA0.x, DA0.y, DA0.z);
        }
        Xa = x4[g0f + 4];
        ogroup(Xb, decay, v, h, gate, xprev, V1, S1, DA0.w, DA1.x, DA1.y, DA1.z); Xb = x4[g0f + 5];
        ogroup(Xc, decay, v, h, gate, xprev, V2, S2, DA1.w, DA2.x, DA2.y, DA2.z); Xc = x4[g0f + 6];
        ogroup(Xd, decay, v, h, gate, xprev, V3, S3, DA2.w, DA3.x, DA3.y, DA3.z); Xd = x4[g0f + 7];
        v4[g0f] = V0; v4[g0f + 1] = V1; v4[g0f + 2] = V2; v4[g0f + 3] = V3;
        s4[g0f] = S0; s4[g0f + 1] = S1; s4[g0f + 2] = S2; s4[g0f + 3] = S3;
    }

#define MQ(q, Dn, Pn) quad_run(q, x4, g0f, decay, v, h, gate, xprev, Xa, Xb, Xc, Xd, \
        Dn##0, Dn##1, Dn##2, Dn##3, Pn##0, Pn##1, Pn##2, Pn##3, v4, s4, d4);
    MQ(1,  DB, DA) MQ(2,  DA, DB) MQ(3,  DB, DA) MQ(4,  DA, DB)
    MQ(5,  DB, DA) MQ(6,  DA, DB) MQ(7,  DB, DA) MQ(8,  DA, DB)
    MQ(9,  DB, DA) MQ(10, DA, DB) MQ(11, DB, DA) MQ(12, DA, DB)
    MQ(13, DB, DA) MQ(14, DA, DB) MQ(15, DB, DA)
#undef MQ

    Est[k * B + b] = make_float2(v, __uint_as_float(h & 127u));   // exit, pre-lookahead

    if (k < K - 1) {                       // lookahead closes dv[t0+L-1]
        float vo_, so_;
        ostep(xla, decay, v, h, gate, vo_, so_, DB3.w, xprev);
    } else {
        DB3.w = ((h & 63u) != 0u) ? 0.0f : xprev;   // dv[T-1]
    }
    d4[g0f + LG - 4] = DB0; d4[g0f + LG - 3] = DB1;
    d4[g0f + LG - 2] = DB2; d4[g0f + LG - 1] = DB3;
}

// ---------------- verify + rare chunk-granular repair (exact by induction) ----------------
__global__ __launch_bounds__(64, 1)
void lif_fix(const float* __restrict__ ode, const float* __restrict__ decay_p,
             float* __restrict__ vout, float* __restrict__ sout, float* __restrict__ dvout,
             const float2* __restrict__ Sst, const float2* __restrict__ Est, int B) {
    const int b = blockIdx.x * 64 + threadIdx.x;
    const float decay = decay_p[0];

    float2 E = Est[b];                     // chunk 0 exit — exact
    for (int k = 1; k < K; ++k) {
        float2 S = Sst[k * B + b];
        bool match = (S.x == E.x) && (__float_as_uint(S.y) == __float_as_uint(E.y));
        if (match) { E = Est[k * B + b]; continue; }

        // rerun chunk k from exact entry E, rewriting its outputs
        const size_t bt = (size_t)b * T;
        const float4* __restrict__ x4 = (const float4*)(ode + bt);
        float4* __restrict__ v4 = (float4*)(vout + bt);
        float4* __restrict__ s4 = (float4*)(sout + bt);
        float4* __restrict__ d4 = (float4*)(dvout + bt);
        const int g0f = k * LG;

        float v = E.x; unsigned h = __float_as_uint(E.y);
        bool gate = (h & 31u) != 0u;
        float xprev = 0.0f;
        float4 pend;

        float4 X  = x4[g0f];
        float4 Xn = x4[g0f + 1];
        {   // group 0: close (dv[t0-1]) owned by chunk k-1's (exact) lookahead
            float4 vo, so; float cl;
            ogroup(X, decay, v, h, gate, xprev, vo, so, cl, pend.x, pend.y, pend.z);
            v4[g0f] = vo; s4[g0f] = so;
        }
        for (int c = 1; c < LG; ++c) {
            X = Xn;
            Xn = x4[g0f + (c + 1 < LG ? c + 1 : LG - 1)];
            float4 vo, so; float px, py, pz;
            ogroup(X, decay, v, h, gate, xprev, vo, so, pend.w, px, py, pz);
            d4[g0f + c - 1] = pend;
            pend.x = px; pend.y = py; pend.z = pz;
            v4[g0f + c] = vo; s4[g0f + c] = so;
        }
        E = make_float2(v, __uint_as_float(h & 127u));   // corrected exit
        if (k < K - 1) {
            float xla = ode[bt + (size_t)(k + 1) * L];
            float vo_, so_;
            ostep(xla, decay, v, h, gate, vo_, so_, pend.w, xprev);
        } else {
            pend.w = ((h & 63u) != 0u) ? 0.0f : xprev;
        }
        d4[g0f + LG - 1] = pend;
    }
}

extern "C" void kernel_launch(void* const* d_in, const int* in_sizes, int n_in,
                              void* d_out, int out_size, void* d_ws, size_t ws_size,
                              hipStream_t stream) {
    const float* ode   = (const float*)d_in[0];
    const float* decay = (const float*)d_in[1];
    float* out = (float*)d_out;

    const int BT = in_sizes[0];            // B*T
    const int B  = BT / T;                 // 2048

    float* vout  = out;
    float* sout  = out + (size_t)BT;
    float* dvout = out + 2 * (size_t)BT;

    float2* Sst = (float2*)d_ws;           // [K][B]
    float2* Est = Sst + (size_t)K * B;     // [K][B]  (512 KB total)

    lif_spec<<<dim3((B * K) / 64), dim3(64), 0, stream>>>(ode, decay, vout, sout, dvout,
                                                          Sst, Est, B);
    lif_fix<<<dim3(B / 64), dim3(64), 0, stream>>>(ode, decay, vout, sout, dvout,
                                                   Sst, Est, B);
}